// Round 22
// baseline (322.091 us; speedup 1.0000x reference)
//
#include <hip/hip_runtime.h>
#include <hip/hip_bf16.h>
#include <hip/hip_fp16.h>

typedef __hip_bfloat16 bf16;
typedef unsigned int   u32;
typedef unsigned short u16;

#define HW 4096
#define NB 4

__device__ __forceinline__ float blo(u32 v){ return __uint_as_float(v << 16); }
__device__ __forceinline__ float bhi(u32 v){ return __uint_as_float(v & 0xffff0000u); }
__device__ __forceinline__ u32 pack2(float a, float b){
  union { bf16 h; u16 u; } ua, ub;
  ua.h = __float2bfloat16(a); ub.h = __float2bfloat16(b);
  return (u32)ua.u | ((u32)ub.u << 16);
}

// ---- transpose dw[c][K2] -> dwTb[tt][128] bf16-pairs ----
__global__ __launch_bounds__(128) void k_dwT(const float* __restrict__ dw, u32* __restrict__ dwTb, int K2){
  int tt = blockIdx.x;
  int c0 = threadIdx.x * 2;
  dwTb[tt*128 + threadIdx.x] = pack2(dw[(size_t)c0*K2 + tt], dw[(size_t)(c0+1)*K2 + tt]);
}

// ---- transpose x NCHW f32 -> xh NHWC bf16 ----
__global__ __launch_bounds__(256) void k_transpose(const float* __restrict__ x, bf16* __restrict__ xh){
  __shared__ float tile[64][65];
  int t = threadIdx.x, blk = blockIdx.x;
  int ct = blk & 3, pt = (blk >> 2) & 63, b = blk >> 8;
  int lp = t & 63, l4 = t >> 6;
  #pragma unroll
  for (int i = 0; i < 16; ++i){
    int cl = l4 + 4*i;
    tile[cl][lp] = x[((size_t)(b*256 + ct*64 + cl))*HW + pt*64 + lp];
  }
  __syncthreads();
  #pragma unroll
  for (int i = 0; i < 16; ++i){
    int pl = l4 + 4*i;
    xh[((size_t)b*HW + pt*64 + pl)*256 + ct*64 + lp] = __float2bfloat16(tile[lp][pl]);
  }
}

// ---- tiled 1x1 conv: NHWC bf16 in -> NCHW f32 out ----
__global__ __launch_bounds__(256) void k_c1x1_nhwc(const bf16* __restrict__ a, const float* __restrict__ w,
                                                   const float* __restrict__ bias, float* __restrict__ out,
                                                   int OC, int OCB){
  __shared__ u32   a2[32*129];
  __shared__ float w2[50*65];
  int t = threadIdx.x;
  int pix0 = blockIdx.x * 32;
  int oc0  = blockIdx.y * OCB;
  int ocnt = min(OCB, OC - oc0);
  const u32* a32 = (const u32*)a;
  int j = t & 127, half = t >> 7;
  #pragma unroll
  for (int ii = 0; ii < 16; ++ii){
    int i = half*16 + ii;
    a2[i*129 + j] = a32[(size_t)(pix0 + i)*128 + j];
  }
  int oc_l = t >> 2, pg = t & 3;
  float acc[8];
  float bv = (oc_l < ocnt) ? bias[oc0 + oc_l] : 0.f;
  #pragma unroll
  for (int q = 0; q < 8; ++q) acc[q] = bv;
  for (int c0 = 0; c0 < 256; c0 += 64){
    __syncthreads();
    for (int idx = t; idx < ocnt*64; idx += 256){
      int o = idx >> 6, jj = idx & 63;
      w2[o*65 + jj] = w[(size_t)(oc0 + o)*256 + c0 + jj];
    }
    __syncthreads();
    if (oc_l < ocnt){
      #pragma unroll 8
      for (int jj2 = 0; jj2 < 32; ++jj2){
        float wlo = w2[oc_l*65 + 2*jj2], whi = w2[oc_l*65 + 2*jj2 + 1];
        #pragma unroll
        for (int q = 0; q < 8; ++q){
          u32 av = a2[(pg*8 + q)*129 + (c0 >> 1) + jj2];
          acc[q] += blo(av)*wlo + bhi(av)*whi;
        }
      }
    }
  }
  if (oc_l < ocnt){
    int b = pix0 >> 12, pr = (pix0 & 4095) + pg*8;
    float* po = out + (size_t)(b*OC + oc0 + oc_l)*HW + pr;
    ((float4*)po)[0] = make_float4(acc[0], acc[1], acc[2], acc[3]);
    ((float4*)po)[1] = make_float4(acc[4], acc[5], acc[6], acc[7]);
  }
}

// ---- depthwise 3x3 pad1, f32 -> f32 ----
__global__ __launch_bounds__(256) void k_dw3(const float* __restrict__ in, const float* __restrict__ w,
                                             const float* __restrict__ bias, float* __restrict__ out, int OC){
  int bo = blockIdx.x;
  int oc = bo % OC;
  int p  = blockIdx.y*256 + threadIdx.x;
  int y = p >> 6, x = p & 63;
  const float* ib = in + (size_t)bo*HW;
  float acc = bias[oc];
  #pragma unroll
  for (int dy = 0; dy < 3; ++dy){
    int yy = y + dy - 1;
    if (yy < 0 || yy > 63) continue;
    #pragma unroll
    for (int dx = 0; dx < 3; ++dx){
      int xx = x + dx - 1;
      if (xx < 0 || xx > 63) continue;
      acc += ib[yy*64 + xx] * w[oc*9 + dy*3 + dx];
    }
  }
  out[(size_t)bo*HW + p] = acc;
}

// ---- fused deformable depthwise: precomp-in-LDS + NHWC gathers + global bf16 dw ----
// block: 256 thr = 8 px x 32 channel-groups; grid NB*512; LDS ~4KB
template<int K, int PAD, int DIL, int UNR>
__global__ __launch_bounds__(256) void k_deform_f(
    const bf16* __restrict__ xh, const float* __restrict__ off,
    const u32* __restrict__ dwTb, bf16* __restrict__ oh){
  constexpr int K2 = K*K;
  __shared__ uint2 lw[K2][8];
  __shared__ u16   la[K2][8];
  int t  = threadIdx.x;
  int cg = t & 31;
  int pl = t >> 5;
  int blk = blockIdx.x;        // b*512 + ptile
  int b   = blk >> 9;
  int p0  = (blk & 511) * 8;
  // fused precomp: 8*K2 table entries from offsets
  for (int e = t; e < 8*K2; e += 256){
    int tt = e >> 3, pxl = e & 7;
    int p  = p0 + pxl;
    int yi = p >> 6, xi = p & 63;
    const float* ob = off + ((size_t)(b*2*K2) + 2*tt)*HW + p;
    float dy = ob[0];
    float dx = ob[HW];
    float py = (float)(yi + (tt/K)*DIL - PAD) + dy;
    float px = (float)(xi + (tt%K)*DIL - PAD) + dx;
    float fy = floorf(py), fx = floorf(px);
    float ty = py - fy, tx = px - fx;
    int iy = (int)fy, ix = (int)fx;
    int sy = min(max(iy, 0), 62);
    int sx = min(max(ix, 0), 62);
    float wy0 = (sy   == iy) ? (1.f-ty) : ((sy   == iy+1) ? ty : 0.f);
    float wy1 = (sy+1 == iy) ? (1.f-ty) : ((sy+1 == iy+1) ? ty : 0.f);
    float wx0 = (sx   == ix) ? (1.f-tx) : ((sx   == ix+1) ? tx : 0.f);
    float wx1 = (sx+1 == ix) ? (1.f-tx) : ((sx+1 == ix+1) ? tx : 0.f);
    u32 lo = (u32)__half_as_ushort(__float2half(wy0*wx0))
           | ((u32)__half_as_ushort(__float2half(wy0*wx1)) << 16);
    u32 hi = (u32)__half_as_ushort(__float2half(wy1*wx0))
           | ((u32)__half_as_ushort(__float2half(wy1*wx1)) << 16);
    lw[tt][pxl] = make_uint2(lo, hi);
    la[tt][pxl] = (u16)(sy*64 + sx);
  }
  __syncthreads();
  const bf16* xb = xh + (size_t)b*HW*256;
  float acc[8];
  #pragma unroll
  for (int j = 0; j < 8; ++j) acc[j] = 0.f;
  for (int t0 = 0; t0 < K2; t0 += UNR){
    #pragma unroll
    for (int u = 0; u < UNR; ++u){
      int tt = t0 + u;
      uint2 wv = lw[tt][pl];
      int   a  = la[tt][pl];
      uint4 dpk = *(const uint4*)&dwTb[tt*128 + cg*4];   // bf16 pairs, L2-hot broadcast
      float W00 = __half2float(__ushort_as_half((u16)(wv.x & 0xffffu)));
      float W01 = __half2float(__ushort_as_half((u16)(wv.x >> 16)));
      float W10 = __half2float(__ushort_as_half((u16)(wv.y & 0xffffu)));
      float W11 = __half2float(__ushort_as_half((u16)(wv.y >> 16)));
      const bf16* base = xb + (size_t)a*256 + cg*8;
      uint4 r00 = *(const uint4*)(base);
      uint4 r01 = *(const uint4*)(base + 256);
      uint4 r10 = *(const uint4*)(base + 64*256);
      uint4 r11 = *(const uint4*)(base + 65*256);
      const u32 q00[4] = {r00.x, r00.y, r00.z, r00.w};
      const u32 q01[4] = {r01.x, r01.y, r01.z, r01.w};
      const u32 q10[4] = {r10.x, r10.y, r10.z, r10.w};
      const u32 q11[4] = {r11.x, r11.y, r11.z, r11.w};
      const u32 dq[4]  = {dpk.x, dpk.y, dpk.z, dpk.w};
      #pragma unroll
      for (int q = 0; q < 4; ++q){
        float sl = W00*blo(q00[q]) + W01*blo(q01[q]) + W10*blo(q10[q]) + W11*blo(q11[q]);
        float sh = W00*bhi(q00[q]) + W01*bhi(q01[q]) + W10*bhi(q10[q]) + W11*bhi(q11[q]);
        acc[2*q]   += blo(dq[q]) * sl;
        acc[2*q+1] += bhi(dq[q]) * sh;
      }
    }
  }
  size_t op = ((size_t)b*HW + p0 + pl)*256 + cg*8;
  uint4 ov;
  ov.x = pack2(acc[0], acc[1]); ov.y = pack2(acc[2], acc[3]);
  ov.z = pack2(acc[4], acc[5]); ov.w = pack2(acc[6], acc[7]);
  *(uint4*)(oh + op) = ov;
}

// ---- final 1x1 + x-multiply: attn NHWC bf16 in, out NCHW f32 ----
__global__ __launch_bounds__(256) void k_final(const bf16* __restrict__ attnh, const float* __restrict__ w1,
                                               const float* __restrict__ b1, const float* __restrict__ x,
                                               float* __restrict__ out){
  __shared__ float at[256][33];
  __shared__ float wt[256][17];
  int t   = threadIdx.x;
  int blk = blockIdx.x;
  int b   = blk >> 7;
  int p0  = (blk & 127) * 32;
  for (int i = 0; i < 32; ++i)
    at[t][i] = __bfloat162float(attnh[((size_t)b*HW + p0 + i)*256 + t]);
  float acc[32];
  float bv = b1[t];
  for (int i = 0; i < 32; ++i) acc[i] = bv;
  for (int c0 = 0; c0 < 256; c0 += 16){
    __syncthreads();
    for (int k = 0; k < 16; ++k){
      int idx = k*256 + t;
      wt[idx >> 4][idx & 15] = w1[(idx >> 4)*256 + c0 + (idx & 15)];
    }
    __syncthreads();
    for (int j = 0; j < 16; ++j){
      float wv = wt[t][j];
      const float* ar = &at[c0 + j][0];
      for (int i = 0; i < 32; ++i)
        acc[i] += wv * ar[i];
    }
  }
  size_t gi = ((size_t)(b*256 + t))*HW + p0;
  for (int i = 0; i < 32; ++i)
    out[gi + i] = acc[i] * x[gi + i];
}

extern "C" void kernel_launch(void* const* d_in, const int* in_sizes, int n_in,
                              void* d_out, int out_size, void* d_ws, size_t ws_size,
                              hipStream_t stream){
  const float* x   = (const float*)d_in[0];
  const float* aw0 = (const float*)d_in[1];
  const float* ab0 = (const float*)d_in[2];
  const float* ow0 = (const float*)d_in[3];
  const float* ob0 = (const float*)d_in[4];
  const float* dw0 = (const float*)d_in[5];
  const float* aw1 = (const float*)d_in[6];
  const float* ab1 = (const float*)d_in[7];
  const float* ow1 = (const float*)d_in[8];
  const float* ob1 = (const float*)d_in[9];
  const float* dw1 = (const float*)d_in[10];
  const float* w1  = (const float*)d_in[11];
  const float* b1  = (const float*)d_in[12];
  float* O = (float*)d_out;

  // ws regions:
  //  R0 @0   (8M): xh NHWC bf16 -> XC1 f32 (6.42M) -> A1h NHWC bf16 (8M)
  //  R1 @8M  (8M): XC0(3.28M)+OF0(3.28M) -> OF1 f32 (6.42M)
  //  R2 @16M (8M): A0h NHWC bf16
  //  R3 @24M     : dwTb0 (12.8K) + dwTb1 (25.1K)
  const size_t MB8 = 8388608;
  char* ws = (char*)d_ws;
  bf16*  xh    = (bf16*) (ws);
  float* XC1   = (float*)(ws);
  bf16*  A1h   = (bf16*) (ws);
  float* XC0   = (float*)(ws + MB8);
  float* OF0   = (float*)(ws + MB8 + 3276800);
  float* OF1   = (float*)(ws + MB8);
  bf16*  A0h   = (bf16*) (ws + 2*MB8);
  u32*   dwTb0 = (u32*)  (ws + 3*MB8);
  u32*   dwTb1 = (u32*)  (ws + 3*MB8 + 131072);

  // prep
  k_dwT<<<25, 128, 0, stream>>>(dw0, dwTb0, 25);
  k_dwT<<<49, 128, 0, stream>>>(dw1, dwTb1, 49);
  k_transpose<<<1024, 256, 0, stream>>>(x, xh);
  // block 0 (K=5, pad 2, dil 1)
  k_c1x1_nhwc<<<dim3(512, 1), 256, 0, stream>>>(xh, aw0, ab0, XC0, 50, 50);
  k_dw3<<<dim3(NB*50, 16), 256, 0, stream>>>(XC0, ow0, ob0, OF0, 50);
  k_deform_f<5,2,1,5><<<NB*512, 256, 0, stream>>>(xh, OF0, dwTb0, A0h);
  // block 1 (K=7, pad 9, dil 3)  [xh dead -> XC1@R0; XC0/OF0 dead -> OF1@R1]
  k_c1x1_nhwc<<<dim3(512, 2), 256, 0, stream>>>(A0h, aw1, ab1, XC1, 98, 49);
  k_dw3<<<dim3(NB*98, 16), 256, 0, stream>>>(XC1, ow1, ob1, OF1, 98);
  k_deform_f<7,9,3,7><<<NB*512, 256, 0, stream>>>(A0h, OF1, dwTb1, A1h);  // XC1 dead -> A1h@R0
  // final 1x1 + x-multiply -> d_out
  k_final<<<NB*128, 256, 0, stream>>>(A1h, w1, b1, x, O);
}

// Round 23
// 267.489 us; speedup vs baseline: 1.2041x; 1.2041x over previous
//
#include <hip/hip_runtime.h>
#include <hip/hip_bf16.h>
#include <hip/hip_fp16.h>

typedef __hip_bfloat16 bf16;
typedef unsigned int   u32;
typedef unsigned short u16;

#define HW 4096
#define NB 4

__device__ __forceinline__ float blo(u32 v){ return __uint_as_float(v << 16); }
__device__ __forceinline__ float bhi(u32 v){ return __uint_as_float(v & 0xffff0000u); }
__device__ __forceinline__ u32 pack2(float a, float b){
  union { bf16 h; u16 u; } ua, ub;
  ua.h = __float2bfloat16(a); ub.h = __float2bfloat16(b);
  return (u32)ua.u | ((u32)ub.u << 16);
}

// ---- transpose dw[c][K2] -> dwTb[tt][128] bf16-pairs ----
__global__ __launch_bounds__(128) void k_dwT(const float* __restrict__ dw, u32* __restrict__ dwTb, int K2){
  int tt = blockIdx.x;
  int c0 = threadIdx.x * 2;
  dwTb[tt*128 + threadIdx.x] = pack2(dw[(size_t)c0*K2 + tt], dw[(size_t)(c0+1)*K2 + tt]);
}

// ---- transpose x NCHW f32 -> xh NHWC bf16 ----
__global__ __launch_bounds__(256) void k_transpose(const float* __restrict__ x, bf16* __restrict__ xh){
  __shared__ float tile[64][65];
  int t = threadIdx.x, blk = blockIdx.x;
  int ct = blk & 3, pt = (blk >> 2) & 63, b = blk >> 8;
  int lp = t & 63, l4 = t >> 6;
  #pragma unroll
  for (int i = 0; i < 16; ++i){
    int cl = l4 + 4*i;
    tile[cl][lp] = x[((size_t)(b*256 + ct*64 + cl))*HW + pt*64 + lp];
  }
  __syncthreads();
  #pragma unroll
  for (int i = 0; i < 16; ++i){
    int pl = l4 + 4*i;
    xh[((size_t)b*HW + pt*64 + pl)*256 + ct*64 + lp] = __float2bfloat16(tile[lp][pl]);
  }
}

// ---- tiled 1x1 conv: NHWC bf16 in -> NCHW f32 out ----
__global__ __launch_bounds__(256) void k_c1x1_nhwc(const bf16* __restrict__ a, const float* __restrict__ w,
                                                   const float* __restrict__ bias, float* __restrict__ out,
                                                   int OC, int OCB){
  __shared__ u32   a2[32*129];
  __shared__ float w2[50*65];
  int t = threadIdx.x;
  int pix0 = blockIdx.x * 32;
  int oc0  = blockIdx.y * OCB;
  int ocnt = min(OCB, OC - oc0);
  const u32* a32 = (const u32*)a;
  int j = t & 127, half = t >> 7;
  #pragma unroll
  for (int ii = 0; ii < 16; ++ii){
    int i = half*16 + ii;
    a2[i*129 + j] = a32[(size_t)(pix0 + i)*128 + j];
  }
  int oc_l = t >> 2, pg = t & 3;
  float acc[8];
  float bv = (oc_l < ocnt) ? bias[oc0 + oc_l] : 0.f;
  #pragma unroll
  for (int q = 0; q < 8; ++q) acc[q] = bv;
  for (int c0 = 0; c0 < 256; c0 += 64){
    __syncthreads();
    for (int idx = t; idx < ocnt*64; idx += 256){
      int o = idx >> 6, jj = idx & 63;
      w2[o*65 + jj] = w[(size_t)(oc0 + o)*256 + c0 + jj];
    }
    __syncthreads();
    if (oc_l < ocnt){
      #pragma unroll 8
      for (int jj2 = 0; jj2 < 32; ++jj2){
        float wlo = w2[oc_l*65 + 2*jj2], whi = w2[oc_l*65 + 2*jj2 + 1];
        #pragma unroll
        for (int q = 0; q < 8; ++q){
          u32 av = a2[(pg*8 + q)*129 + (c0 >> 1) + jj2];
          acc[q] += blo(av)*wlo + bhi(av)*whi;
        }
      }
    }
  }
  if (oc_l < ocnt){
    int b = pix0 >> 12, pr = (pix0 & 4095) + pg*8;
    float* po = out + (size_t)(b*OC + oc0 + oc_l)*HW + pr;
    ((float4*)po)[0] = make_float4(acc[0], acc[1], acc[2], acc[3]);
    ((float4*)po)[1] = make_float4(acc[4], acc[5], acc[6], acc[7]);
  }
}

// ---- depthwise 3x3 pad1, f32 -> f32 ----
__global__ __launch_bounds__(256) void k_dw3(const float* __restrict__ in, const float* __restrict__ w,
                                             const float* __restrict__ bias, float* __restrict__ out, int OC){
  int bo = blockIdx.x;
  int oc = bo % OC;
  int p  = blockIdx.y*256 + threadIdx.x;
  int y = p >> 6, x = p & 63;
  const float* ib = in + (size_t)bo*HW;
  float acc = bias[oc];
  #pragma unroll
  for (int dy = 0; dy < 3; ++dy){
    int yy = y + dy - 1;
    if (yy < 0 || yy > 63) continue;
    #pragma unroll
    for (int dx = 0; dx < 3; ++dx){
      int xx = x + dx - 1;
      if (xx < 0 || xx > 63) continue;
      acc += ib[yy*64 + xx] * w[oc*9 + dy*3 + dx];
    }
  }
  out[(size_t)bo*HW + p] = acc;
}

// ---- deform0: R20-proven structure (serialized tap loop) + bf16 dw table ----
// block: 256 thr = 8 px x 32 channel-groups; grid NB*512; LDS ~4KB
template<int K, int PAD, int DIL>
__global__ __launch_bounds__(256) void k_deform_f(
    const bf16* __restrict__ xh, const float* __restrict__ off,
    const u32* __restrict__ dwTb, bf16* __restrict__ oh){
  constexpr int K2 = K*K;
  __shared__ uint2 lw[K2][8];
  __shared__ u16   la[K2][8];
  int t  = threadIdx.x;
  int cg = t & 31;
  int pl = t >> 5;
  int blk = blockIdx.x;
  int b   = blk >> 9;
  int p0  = (blk & 511) * 8;
  for (int e = t; e < 8*K2; e += 256){
    int tt = e >> 3, pxl = e & 7;
    int p  = p0 + pxl;
    int yi = p >> 6, xi = p & 63;
    const float* ob = off + ((size_t)(b*2*K2) + 2*tt)*HW + p;
    float dy = ob[0];
    float dx = ob[HW];
    float py = (float)(yi + (tt/K)*DIL - PAD) + dy;
    float px = (float)(xi + (tt%K)*DIL - PAD) + dx;
    float fy = floorf(py), fx = floorf(px);
    float ty = py - fy, tx = px - fx;
    int iy = (int)fy, ix = (int)fx;
    int sy = min(max(iy, 0), 62);
    int sx = min(max(ix, 0), 62);
    float wy0 = (sy   == iy) ? (1.f-ty) : ((sy   == iy+1) ? ty : 0.f);
    float wy1 = (sy+1 == iy) ? (1.f-ty) : ((sy+1 == iy+1) ? ty : 0.f);
    float wx0 = (sx   == ix) ? (1.f-tx) : ((sx   == ix+1) ? tx : 0.f);
    float wx1 = (sx+1 == ix) ? (1.f-tx) : ((sx+1 == ix+1) ? tx : 0.f);
    u32 lo = (u32)__half_as_ushort(__float2half(wy0*wx0))
           | ((u32)__half_as_ushort(__float2half(wy0*wx1)) << 16);
    u32 hi = (u32)__half_as_ushort(__float2half(wy1*wx0))
           | ((u32)__half_as_ushort(__float2half(wy1*wx1)) << 16);
    lw[tt][pxl] = make_uint2(lo, hi);
    la[tt][pxl] = (u16)(sy*64 + sx);
  }
  __syncthreads();
  const bf16* xb = xh + (size_t)b*HW*256;
  float acc[8];
  #pragma unroll
  for (int j = 0; j < 8; ++j) acc[j] = 0.f;
  for (int tt = 0; tt < K2; ++tt){
    uint2 wv = lw[tt][pl];
    int   a  = la[tt][pl];
    uint4 dpk = *(const uint4*)&dwTb[tt*128 + cg*4];
    float W00 = __half2float(__ushort_as_half((u16)(wv.x & 0xffffu)));
    float W01 = __half2float(__ushort_as_half((u16)(wv.x >> 16)));
    float W10 = __half2float(__ushort_as_half((u16)(wv.y & 0xffffu)));
    float W11 = __half2float(__ushort_as_half((u16)(wv.y >> 16)));
    const bf16* base = xb + (size_t)a*256 + cg*8;
    uint4 r00 = *(const uint4*)(base);
    uint4 r01 = *(const uint4*)(base + 256);
    uint4 r10 = *(const uint4*)(base + 64*256);
    uint4 r11 = *(const uint4*)(base + 65*256);
    const u32 q00[4] = {r00.x, r00.y, r00.z, r00.w};
    const u32 q01[4] = {r01.x, r01.y, r01.z, r01.w};
    const u32 q10[4] = {r10.x, r10.y, r10.z, r10.w};
    const u32 q11[4] = {r11.x, r11.y, r11.z, r11.w};
    const u32 dq[4]  = {dpk.x, dpk.y, dpk.z, dpk.w};
    #pragma unroll
    for (int q = 0; q < 4; ++q){
      float sl = W00*blo(q00[q]) + W01*blo(q01[q]) + W10*blo(q10[q]) + W11*blo(q11[q]);
      float sh = W00*bhi(q00[q]) + W01*bhi(q01[q]) + W10*bhi(q10[q]) + W11*bhi(q11[q]);
      acc[2*q]   += blo(dq[q]) * sl;
      acc[2*q+1] += bhi(dq[q]) * sh;
    }
  }
  size_t op = ((size_t)b*HW + p0 + pl)*256 + cg*8;
  uint4 ov;
  ov.x = pack2(acc[0], acc[1]); ov.y = pack2(acc[2], acc[3]);
  ov.z = pack2(acc[4], acc[5]); ov.w = pack2(acc[6], acc[7]);
  *(uint4*)(oh + op) = ov;
}

// ---- fused deform1 + final 1x1 + x-multiply -> NCHW f32 d_out ----
// Phase 1: R20-proven gather loop -> attn1 tile (256ch x 8px) in LDS (f32).
// Phase 2: k_final-proven chunked w1 matmul; thread = oc; write f32 out.
template<int K, int PAD, int DIL>
__global__ __launch_bounds__(256) void k_deform_final(
    const bf16* __restrict__ xh, const float* __restrict__ off,
    const u32* __restrict__ dwTb, const float* __restrict__ w1,
    const float* __restrict__ b1, const float* __restrict__ x,
    float* __restrict__ out){
  constexpr int K2 = K*K;
  __shared__ float at[8][260];                    // [px][ch] (+4 pad)
  __shared__ __align__(16) char arena[17408];     // phase1: lw+la | phase2: wt[256][17]
  uint2* lw = (uint2*)arena;                      // [K2][8]
  u16*   la = (u16*)(arena + (size_t)K2*8*8);     // [K2][8]
  float* wt = (float*)arena;                      // [256][17]
  int t  = threadIdx.x;
  int cg = t & 31;
  int pl = t >> 5;
  int blk = blockIdx.x;
  int b   = blk >> 9;
  int p0  = (blk & 511) * 8;
  for (int e = t; e < 8*K2; e += 256){
    int tt = e >> 3, pxl = e & 7;
    int p  = p0 + pxl;
    int yi = p >> 6, xi = p & 63;
    const float* ob = off + ((size_t)(b*2*K2) + 2*tt)*HW + p;
    float dy = ob[0];
    float dx = ob[HW];
    float py = (float)(yi + (tt/K)*DIL - PAD) + dy;
    float px = (float)(xi + (tt%K)*DIL - PAD) + dx;
    float fy = floorf(py), fx = floorf(px);
    float ty = py - fy, tx = px - fx;
    int iy = (int)fy, ix = (int)fx;
    int sy = min(max(iy, 0), 62);
    int sx = min(max(ix, 0), 62);
    float wy0 = (sy   == iy) ? (1.f-ty) : ((sy   == iy+1) ? ty : 0.f);
    float wy1 = (sy+1 == iy) ? (1.f-ty) : ((sy+1 == iy+1) ? ty : 0.f);
    float wx0 = (sx   == ix) ? (1.f-tx) : ((sx   == ix+1) ? tx : 0.f);
    float wx1 = (sx+1 == ix) ? (1.f-tx) : ((sx+1 == ix+1) ? tx : 0.f);
    u32 lo = (u32)__half_as_ushort(__float2half(wy0*wx0))
           | ((u32)__half_as_ushort(__float2half(wy0*wx1)) << 16);
    u32 hi = (u32)__half_as_ushort(__float2half(wy1*wx0))
           | ((u32)__half_as_ushort(__float2half(wy1*wx1)) << 16);
    lw[tt*8 + pxl] = make_uint2(lo, hi);
    la[tt*8 + pxl] = (u16)(sy*64 + sx);
  }
  __syncthreads();
  const bf16* xb = xh + (size_t)b*HW*256;
  float acc[8];
  #pragma unroll
  for (int j = 0; j < 8; ++j) acc[j] = 0.f;
  for (int tt = 0; tt < K2; ++tt){
    uint2 wv = lw[tt*8 + pl];
    int   a  = la[tt*8 + pl];
    uint4 dpk = *(const uint4*)&dwTb[tt*128 + cg*4];
    float W00 = __half2float(__ushort_as_half((u16)(wv.x & 0xffffu)));
    float W01 = __half2float(__ushort_as_half((u16)(wv.x >> 16)));
    float W10 = __half2float(__ushort_as_half((u16)(wv.y & 0xffffu)));
    float W11 = __half2float(__ushort_as_half((u16)(wv.y >> 16)));
    const bf16* base = xb + (size_t)a*256 + cg*8;
    uint4 r00 = *(const uint4*)(base);
    uint4 r01 = *(const uint4*)(base + 256);
    uint4 r10 = *(const uint4*)(base + 64*256);
    uint4 r11 = *(const uint4*)(base + 65*256);
    const u32 q00[4] = {r00.x, r00.y, r00.z, r00.w};
    const u32 q01[4] = {r01.x, r01.y, r01.z, r01.w};
    const u32 q10[4] = {r10.x, r10.y, r10.z, r10.w};
    const u32 q11[4] = {r11.x, r11.y, r11.z, r11.w};
    const u32 dq[4]  = {dpk.x, dpk.y, dpk.z, dpk.w};
    #pragma unroll
    for (int q = 0; q < 4; ++q){
      float sl = W00*blo(q00[q]) + W01*blo(q01[q]) + W10*blo(q10[q]) + W11*blo(q11[q]);
      float sh = W00*bhi(q00[q]) + W01*bhi(q01[q]) + W10*bhi(q10[q]) + W11*bhi(q11[q]);
      acc[2*q]   += blo(dq[q]) * sl;
      acc[2*q+1] += bhi(dq[q]) * sh;
    }
  }
  // attn1 tile -> LDS (f32, unrounded)
  ((float4*)&at[pl][cg*8])[0] = make_float4(acc[0], acc[1], acc[2], acc[3]);
  ((float4*)&at[pl][cg*8])[1] = make_float4(acc[4], acc[5], acc[6], acc[7]);
  // phase 2: final 1x1 (thread = oc) + x multiply
  float acc2[8];
  float bv = b1[t];
  #pragma unroll
  for (int i = 0; i < 8; ++i) acc2[i] = bv;
  for (int c0 = 0; c0 < 256; c0 += 16){
    __syncthreads();               // at visible (1st) / wt consumed (later); lw/la dead
    #pragma unroll
    for (int k = 0; k < 16; ++k){
      int idx = k*256 + t;
      wt[(idx >> 4)*17 + (idx & 15)] = w1[(size_t)(idx >> 4)*256 + c0 + (idx & 15)];
    }
    __syncthreads();
    #pragma unroll 4
    for (int j = 0; j < 16; ++j){
      float wv = wt[t*17 + j];
      #pragma unroll
      for (int i = 0; i < 8; ++i)
        acc2[i] += wv * at[i][c0 + j];
    }
  }
  size_t gi = ((size_t)(b*256 + t))*HW + p0;
  float4 xa = ((const float4*)(x + gi))[0];
  float4 xb4 = ((const float4*)(x + gi))[1];
  ((float4*)(out + gi))[0] = make_float4(acc2[0]*xa.x, acc2[1]*xa.y, acc2[2]*xa.z, acc2[3]*xa.w);
  ((float4*)(out + gi))[1] = make_float4(acc2[4]*xb4.x, acc2[5]*xb4.y, acc2[6]*xb4.z, acc2[7]*xb4.w);
}

extern "C" void kernel_launch(void* const* d_in, const int* in_sizes, int n_in,
                              void* d_out, int out_size, void* d_ws, size_t ws_size,
                              hipStream_t stream){
  const float* x   = (const float*)d_in[0];
  const float* aw0 = (const float*)d_in[1];
  const float* ab0 = (const float*)d_in[2];
  const float* ow0 = (const float*)d_in[3];
  const float* ob0 = (const float*)d_in[4];
  const float* dw0 = (const float*)d_in[5];
  const float* aw1 = (const float*)d_in[6];
  const float* ab1 = (const float*)d_in[7];
  const float* ow1 = (const float*)d_in[8];
  const float* ob1 = (const float*)d_in[9];
  const float* dw1 = (const float*)d_in[10];
  const float* w1  = (const float*)d_in[11];
  const float* b1  = (const float*)d_in[12];
  float* O = (float*)d_out;

  // ws regions:
  //  R0 @0   (8M): xh NHWC bf16 -> XC1 f32 (6.42M)
  //  R1 @8M  (8M): XC0(3.28M)+OF0(3.28M) -> OF1 f32 (6.42M)
  //  R2 @16M (8M): A0h NHWC bf16
  //  R3 @24M     : dwTb0 (12.8K) + dwTb1 (25.1K)
  const size_t MB8 = 8388608;
  char* ws = (char*)d_ws;
  bf16*  xh    = (bf16*) (ws);
  float* XC1   = (float*)(ws);
  float* XC0   = (float*)(ws + MB8);
  float* OF0   = (float*)(ws + MB8 + 3276800);
  float* OF1   = (float*)(ws + MB8);
  bf16*  A0h   = (bf16*) (ws + 2*MB8);
  u32*   dwTb0 = (u32*)  (ws + 3*MB8);
  u32*   dwTb1 = (u32*)  (ws + 3*MB8 + 131072);

  // prep
  k_dwT<<<25, 128, 0, stream>>>(dw0, dwTb0, 25);
  k_dwT<<<49, 128, 0, stream>>>(dw1, dwTb1, 49);
  k_transpose<<<1024, 256, 0, stream>>>(x, xh);
  // block 0 (K=5, pad 2, dil 1)
  k_c1x1_nhwc<<<dim3(512, 1), 256, 0, stream>>>(xh, aw0, ab0, XC0, 50, 50);
  k_dw3<<<dim3(NB*50, 16), 256, 0, stream>>>(XC0, ow0, ob0, OF0, 50);
  k_deform_f<5,2,1><<<NB*512, 256, 0, stream>>>(xh, OF0, dwTb0, A0h);
  // block 1 (K=7, pad 9, dil 3)  [xh dead -> XC1@R0; XC0/OF0 dead -> OF1@R1]
  k_c1x1_nhwc<<<dim3(512, 2), 256, 0, stream>>>(A0h, aw1, ab1, XC1, 98, 49);
  k_dw3<<<dim3(NB*98, 16), 256, 0, stream>>>(XC1, ow1, ob1, OF1, 98);
  // fused deform1 + final 1x1 + x-multiply -> d_out
  k_deform_final<7,9,3><<<NB*512, 256, 0, stream>>>(A0h, OF1, dwTb1, w1, b1, x, O);
}